// Round 19
// baseline (164.975 us; speedup 1.0000x reference)
//
#include <hip/hip_runtime.h>
#include <hip/hip_bf16.h>

// Fused attention: out_t[b,d,n] = sum_m softmax_m(Q[b,n,:]·K[b,m,:]/16)[n,m] * V[b,d,m]
// d_out = out_t (16*256*2048 f32) ++ p_attn (16*2048*2048 f32)
//
// Fast path (ws >= 33.6MB): R18 kernel + PV pipelined ONE TILE BEHIND with
// Plds double-buffered (T15): one counted barrier per iter (was 2); PV(t-1)
// MFMA overlaps softmax(t) VALU in the QK->softmax dependency window.
// Parity: iter t writes {Kl[(t+1)&1], Vl[t&1], Pl[t&1]}, reads {Kl[t&1],
// Vl[(t-1)&1], Pl[(t-1)&1]} - disjoint. vmcnt(4) retires stage ops + old NT.
// LDS: Klds 2x32 + Vlds 2x32 + Plds 2x16 = 160KB exactly.

using bf16x8 = __attribute__((ext_vector_type(8))) short;  // 8 bf16 in 4 VGPRs
using f32x4  = __attribute__((ext_vector_type(4))) float;

__device__ __forceinline__ short f2bf(float f) {
    unsigned u = __float_as_uint(f);
    u += 0x7fffu + ((u >> 16) & 1u);   // round-to-nearest-even
    return (short)(u >> 16);
}
__device__ __forceinline__ f32x4 mfma16(bf16x8 a, bf16x8 b, f32x4 c) {
    return __builtin_amdgcn_mfma_f32_16x16x32_bf16(a, b, c, 0, 0, 0);
}

// Counted-wait barrier (T4): stage ops retired, 4 newest NT stores in flight.
__device__ __forceinline__ void bar_vm4() {
    asm volatile("s_waitcnt vmcnt(4) lgkmcnt(0)\n\ts_barrier" ::: "memory");
}

#define AS1(p) ((const __attribute__((address_space(1))) void*)(p))
#define AS3(p) ((__attribute__((address_space(3))) void*)(p))

constexpr float LOG2E = 1.4426950408889634f;

// ---------------------------------------------------------------- convert K,V
__global__ __launch_bounds__(256)
void convert_kv(const float* __restrict__ K, const float* __restrict__ V,
                short* __restrict__ Kb, short* __restrict__ Vb, size_t n8)
{
    size_t i = (size_t)blockIdx.x * 256 + threadIdx.x;
    const float* src;
    short* dst;
    if (i < n8) { src = K; dst = Kb; }
    else        { i -= n8; src = V; dst = Vb; }
    const f32x4* s4 = (const f32x4*)src;
    f32x4 a = __builtin_nontemporal_load(s4 + i * 2);
    f32x4 b = __builtin_nontemporal_load(s4 + i * 2 + 1);
    bf16x8 v;
    v[0] = f2bf(a[0]); v[1] = f2bf(a[1]); v[2] = f2bf(a[2]); v[3] = f2bf(a[3]);
    v[4] = f2bf(b[0]); v[5] = f2bf(b[1]); v[6] = f2bf(b[2]); v[7] = f2bf(b[3]);
    *(bf16x8*)(dst + i * 8) = v;
}

// ---------------------------------------------------------------- fused
// 256 blocks = (b, nb): 16 x 16 blocks of 128 q-rows. 512 thr, 8 waves.
__global__ __launch_bounds__(512, 2)
void fused_attn(const float* __restrict__ Qf, const short* __restrict__ Kb,
                const short* __restrict__ Vb, float* __restrict__ Pout,
                float* __restrict__ outT)
{
    __shared__ __align__(16) short Klds[2][64 * 256];
    __shared__ __align__(16) short Vlds[2][256 * 64];
    __shared__ __align__(16) short Plds[2][128 * 64];
    float* lpart = (float*)Plds;                 // [8][32], pre->main only

    const unsigned g  = blockIdx.x;
    const unsigned wg = (g & 7) * 32 + (g >> 3);   // XCD-chunked, bijective
    const int b  = (int)(wg >> 4);
    const int nb = (int)(wg & 15);

    const int tid  = threadIdx.x;
    const int lane = tid & 63;
    const int wave = tid >> 6;
    const int wn  = wave >> 1;
    const int wm  = wave & 1;
    const int l15 = lane & 15;
    const int l4  = lane >> 4;

    const short* Kbase = Kb + (size_t)b * (2048 * 256);
    const short* Vbase = Vb + (size_t)b * (256 * 2048);

    // ---- hoist Q fragments, f32 -> bf16 inline (row=l15, k=l4*8+j)
    const float* Qp = Qf + ((size_t)b * 2048 + (size_t)nb * 128) * 256;
    bf16x8 qf[2][8];
#pragma unroll
    for (int mf = 0; mf < 2; mf++)
#pragma unroll
        for (int ks = 0; ks < 8; ks++) {
            const float* src = Qp + (size_t)(wn * 32 + mf * 16 + l15) * 256
                             + ks * 32 + l4 * 8;
            const f32x4 a = *(const f32x4*)src;
            const f32x4 c = *(const f32x4*)(src + 4);
            bf16x8 v;
            v[0] = f2bf(a[0] * 0.0625f); v[1] = f2bf(a[1] * 0.0625f);
            v[2] = f2bf(a[2] * 0.0625f); v[3] = f2bf(a[3] * 0.0625f);
            v[4] = f2bf(c[0] * 0.0625f); v[5] = f2bf(c[1] * 0.0625f);
            v[6] = f2bf(c[2] * 0.0625f); v[7] = f2bf(c[3] * 0.0625f);
            qf[mf][ks] = v;
        }

    // ---- staging (R8-verified formulas)
    auto stage_k = [&](int t, int buf) {       // 64-row K tile -> Klds[buf]
#pragma unroll
        for (int i = 0; i < 4; i++) {
            int ml = i * 16 + wave * 2 + (lane >> 5);
            int c  = lane & 31;
            int cs = (c & 24) | ((c ^ ml) & 7);
            __builtin_amdgcn_global_load_lds(
                AS1(Kbase + (size_t)(t * 64 + ml) * 256 + cs * 8),
                AS3(&Klds[buf][i * 4096 + wave * 512]), 16, 0, 0);
        }
    };
    auto stage_v = [&](int t, int buf) {       // 256x64 V tile -> Vlds[buf]
#pragma unroll
        for (int i = 0; i < 4; i++) {
            int d  = i * 64 + wave * 8 + (lane >> 3);
            int c  = lane & 7;
            int cs = c ^ (d & 7);
            __builtin_amdgcn_global_load_lds(
                AS1(Vbase + (size_t)d * 2048 + t * 64 + cs * 8),
                AS3(&Vlds[buf][i * 4096 + wave * 512]), 16, 0, 0);
        }
    };
    auto stage_k128 = [&](int t, int which) {  // 128-row K tile (pre-loop)
#pragma unroll
        for (int i = 0; i < 8; i++) {
            int ml = i * 16 + wave * 2 + (lane >> 5);
            int c  = lane & 31;
            int cs = (c & 24) | ((c ^ ml) & 7);
            short* dst = which ? &Vlds[0][0] : &Klds[0][0];
            __builtin_amdgcn_global_load_lds(
                AS1(Kbase + (size_t)(t * 128 + ml) * 256 + cs * 8),
                AS3(dst + i * 4096 + wave * 512), 16, 0, 0);
        }
    };

    // ---- main-loop QK (swapped operands, + setprio)
    auto qkt = [&](int buf, f32x4 sacT[2][2]) {
        __builtin_amdgcn_s_setprio(1);
#pragma unroll
        for (int ks = 0; ks < 8; ks++) {
            bf16x8 kf[2];
#pragma unroll
            for (int nf = 0; nf < 2; nf++) {
                int m  = wm * 32 + nf * 16 + l15;
                int ch = (ks * 4 + l4) ^ (m & 7);
                kf[nf] = *(const bf16x8*)((const char*)&Klds[buf][0] + m * 512 + ch * 16);
            }
#pragma unroll
            for (int mf = 0; mf < 2; mf++)
#pragma unroll
                for (int nf = 0; nf < 2; nf++)
                    sacT[mf][nf] = mfma16(kf[nf], qf[mf][ks], sacT[mf][nf]);
        }
        __builtin_amdgcn_s_setprio(0);
    };
    // ---- pre-loop QK over a 128-row tile
    auto qkt128 = [&](int which, f32x4 sacT[2][4]) {
        const char* kb = which ? (const char*)&Vlds[0][0] : (const char*)&Klds[0][0];
        __builtin_amdgcn_s_setprio(1);
#pragma unroll
        for (int ks = 0; ks < 8; ks++) {
            bf16x8 kf[4];
#pragma unroll
            for (int nf = 0; nf < 4; nf++) {
                int m  = wm * 64 + nf * 16 + l15;
                int ch = (ks * 4 + l4) ^ (m & 7);
                kf[nf] = *(const bf16x8*)(kb + m * 512 + ch * 16);
            }
#pragma unroll
            for (int mf = 0; mf < 2; mf++)
#pragma unroll
                for (int nf = 0; nf < 4; nf++)
                    sacT[mf][nf] = mfma16(kf[nf], qf[mf][ks], sacT[mf][nf]);
        }
        __builtin_amdgcn_s_setprio(0);
    };
    // ---- PV for tile tt (reads Vlds[tt&1], Plds[tt&1])
    f32x4 oac[4][4];
#pragma unroll
    for (int i = 0; i < 4; i++)
#pragma unroll
        for (int j = 0; j < 4; j++)
            oac[i][j] = f32x4{0.f, 0.f, 0.f, 0.f};
    auto pv = [&](int tt) {
        const char* vb_ = (const char*)&Vlds[tt & 1][0];
        const char* pb_ = (const char*)&Plds[tt & 1][0];
        __builtin_amdgcn_s_setprio(1);
#pragma unroll
        for (int ksl = 0; ksl < 2; ksl++) {
            bf16x8 vf[4], pf[4];
#pragma unroll
            for (int mf4 = 0; mf4 < 4; mf4++) {
                const int d  = wn * 64 + mf4 * 16 + l15;
                const int ch = (ksl * 4 + l4) ^ (d & 7);
                vf[mf4] = *(const bf16x8*)(vb_ + d * 128 + ch * 16);
            }
#pragma unroll
            for (int nf4 = 0; nf4 < 4; nf4++) {
                const int n  = wm * 64 + nf4 * 16 + l15;
                const int ch = (ksl * 4 + l4) ^ (n & 7);
                pf[nf4] = *(const bf16x8*)(pb_ + n * 128 + ch * 16);
            }
#pragma unroll
            for (int mf4 = 0; mf4 < 4; mf4++)
#pragma unroll
                for (int nf4 = 0; nf4 < 4; nf4++)
                    oac[mf4][nf4] = mfma16(vf[mf4], pf[nf4], oac[mf4][nf4]);
        }
        __builtin_amdgcn_s_setprio(0);
    };

    // ================= pre-loop: l[n], 16 x 128-row K tiles =================
    float lacc[2] = {0.f, 0.f};
    stage_k128(0, 0);
    for (int t = 0; t < 16; t++) {
        __syncthreads();                         // tile t staged & drained
        if (t + 1 < 16) stage_k128(t + 1, (t + 1) & 1);
        f32x4 sacT[2][4];
#pragma unroll
        for (int mf = 0; mf < 2; mf++)
#pragma unroll
            for (int nf = 0; nf < 4; nf++)
                sacT[mf][nf] = f32x4{0.f, 0.f, 0.f, 0.f};
        qkt128(t & 1, sacT);
#pragma unroll
        for (int mf = 0; mf < 2; mf++)
#pragma unroll
            for (int nf = 0; nf < 4; nf++)
#pragma unroll
                for (int r = 0; r < 4; r++)
                    lacc[mf] += exp2f(sacT[mf][nf][r] * LOG2E);
    }
    stage_k(0, 0);                               // main K(0); Klds free (t=15 read Vlds)
    // combine 4 l4-groups (same n = l15): butterfly over lane bits 4,5
#pragma unroll
    for (int mf = 0; mf < 2; mf++) {
        lacc[mf] += __shfl_xor(lacc[mf], 16);
        lacc[mf] += __shfl_xor(lacc[mf], 32);
    }
    if (l4 == 0) {
        lpart[wave * 32 + 0 * 16 + l15] = lacc[0];
        lpart[wave * 32 + 1 * 16 + l15] = lacc[1];
    }
    __syncthreads();                             // lpart published; stage_k(0) drained
    float rl[2];
#pragma unroll
    for (int mf = 0; mf < 2; mf++)
        rl[mf] = 1.0f / (lpart[(wn * 2 + 0) * 32 + mf * 16 + l15] +
                         lpart[(wn * 2 + 1) * 32 + mf * 16 + l15]);
    __syncthreads();                             // rl reads done -> Plds reusable

    // ================= main loop (1 counted barrier/iter, PV lagged) ========
    float* prow = Pout + ((size_t)b * 2048 + (size_t)nb * 128) * 2048;

    for (int t = 0; t < 32; t++) {
        f32x4 sacT[2][2];
#pragma unroll
        for (int mf = 0; mf < 2; mf++)
#pragma unroll
            for (int nf = 0; nf < 2; nf++)
                sacT[mf][nf] = f32x4{0.f, 0.f, 0.f, 0.f};
        qkt(t & 1, sacT);

        // prefetch: K(t+1) -> Kl[(t+1)&1], V(t) -> Vl[t&1] (used by PV at t+1)
        if (t + 1 < 32) stage_k(t + 1, (t + 1) & 1);
        stage_v(t, t & 1);

        // PV(t-1): fills the QK(t)->softmax(t) dependency window (MFMA pipe)
        if (t > 0) pv(t - 1);

        // softmax(t) (VALU) + NT p_attn + pack -> Pl[t&1]
        f32x4 pv4[2][2];
#pragma unroll
        for (int mf = 0; mf < 2; mf++)
#pragma unroll
            for (int nf = 0; nf < 2; nf++)
#pragma unroll
                for (int r = 0; r < 4; r++)
                    pv4[mf][nf][r] = exp2f(sacT[mf][nf][r] * LOG2E) * rl[mf];
#pragma unroll
        for (int mf = 0; mf < 2; mf++)
#pragma unroll
            for (int nf = 0; nf < 2; nf++) {
                const int n  = wn * 32 + mf * 16 + l15;
                const int m  = t * 64 + wm * 32 + nf * 16 + l4 * 4;
                __builtin_nontemporal_store(pv4[mf][nf],
                    (f32x4*)(prow + (size_t)n * 2048 + m));
            }
#pragma unroll
        for (int mf = 0; mf < 2; mf++)
#pragma unroll
            for (int nf = 0; nf < 2; nf++) {
                short4 ps;
                ps.x = f2bf(pv4[mf][nf][0]); ps.y = f2bf(pv4[mf][nf][1]);
                ps.z = f2bf(pv4[mf][nf][2]); ps.w = f2bf(pv4[mf][nf][3]);
                const int n  = wn * 32 + mf * 16 + l15;
                const int mb = wm * 32 + nf * 16 + l4 * 4;
                const int ch = (mb >> 3) ^ (n & 7);
                *(short4*)((char*)&Plds[t & 1][0] + n * 128 + ch * 16 + (mb & 7) * 2) = ps;
            }

        // end-of-iter: retires stage_k(t+1)+stage_v(t)+NT(t-1); publishes
        // Kl[(t+1)&1], Vl[t&1], Pl[t&1]. 4 newest NT stores stay in flight.
        bar_vm4();
    }
    pv(31);                                      // drain the pipeline

    // ---- epilogue: out_t[b][d][nb*128 + n]
    float* op = outT + (size_t)b * (256 * 2048) + (size_t)nb * 128;
#pragma unroll
    for (int mf4 = 0; mf4 < 4; mf4++)
#pragma unroll
        for (int nf4 = 0; nf4 < 4; nf4++)
#pragma unroll
            for (int r = 0; r < 4; r++) {
                int d = wn * 64 + mf4 * 16 + l4 * 4 + r;
                int n = wm * 64 + nf4 * 16 + l15;
                op[(size_t)d * 2048 + n] = oac[mf4][nf4][r];
            }
}

// ------------------------------------------- legacy f32 GEMM (fallback only)
template<int BM, int BN, int BK>
__global__ __launch_bounds__(256)
void gemm_abt(const float* __restrict__ A, const float* __restrict__ B,
              float* __restrict__ C, int M, int N, int K,
              long strideA, long strideB, long strideC, float scale)
{
    const int b  = blockIdx.z;
    const int bm = blockIdx.y;
    const int bn = blockIdx.x;
    A += (size_t)b * strideA;
    B += (size_t)b * strideB;
    C += (size_t)b * strideC;

    constexpr int LDT = BK + 8;
    __shared__ __align__(16) short Alds[BM][LDT];
    __shared__ __align__(16) short Blds[BN][LDT];

    const int tid  = threadIdx.x;
    const int lane = tid & 63;
    const int wave = tid >> 6;
    const int wr   = wave >> 1;
    const int wc   = wave & 1;

    f32x4 acc[4][4];
#pragma unroll
    for (int m = 0; m < 4; m++)
#pragma unroll
        for (int n = 0; n < 4; n++)
            acc[m][n] = f32x4{0.f, 0.f, 0.f, 0.f};

    const float* Ab = A + (size_t)(bm * BM) * K;
    const float* Bb = B + (size_t)(bn * BN) * K;

    const int tr  = tid >> 4;
    const int tc4 = (tid & 15) << 2;

    for (int k0 = 0; k0 < K; k0 += BK) {
        __syncthreads();
#pragma unroll
        for (int r = tr; r < BM; r += 16) {
            const float4 v = *(const float4*)(Ab + (size_t)r * K + k0 + tc4);
            short4 s;
            s.x = f2bf(v.x); s.y = f2bf(v.y); s.z = f2bf(v.z); s.w = f2bf(v.w);
            *(short4*)&Alds[r][tc4] = s;
        }
#pragma unroll
        for (int r = tr; r < BN; r += 16) {
            const float4 v = *(const float4*)(Bb + (size_t)r * K + k0 + tc4);
            short4 s;
            s.x = f2bf(v.x); s.y = f2bf(v.y); s.z = f2bf(v.z); s.w = f2bf(v.w);
            *(short4*)&Blds[r][tc4] = s;
        }
        __syncthreads();

#pragma unroll
        for (int kk = 0; kk < BK; kk += 32) {
            const int ko = kk + ((lane >> 4) << 3);
            bf16x8 af[4], bfr[4];
#pragma unroll
            for (int m = 0; m < 4; m++)
                af[m] = *(const bf16x8*)&Alds[wr * 64 + m * 16 + (lane & 15)][ko];
#pragma unroll
            for (int n = 0; n < 4; n++)
                bfr[n] = *(const bf16x8*)&Blds[wc * 64 + n * 16 + (lane & 15)][ko];
#pragma unroll
            for (int m = 0; m < 4; m++)
#pragma unroll
                for (int n = 0; n < 4; n++)
                    acc[m][n] = __builtin_amdgcn_mfma_f32_16x16x32_bf16(
                        af[m], bfr[n], acc[m][n], 0, 0, 0);
        }
    }

    float* Cb = C + (size_t)(bm * BM) * N + (size_t)bn * BN;
    const int rbase = wr * 64 + ((lane >> 4) << 2);
    const int cbase = wc * 64 + (lane & 15);
#pragma unroll
    for (int m = 0; m < 4; m++)
#pragma unroll
        for (int n = 0; n < 4; n++)
#pragma unroll
            for (int r = 0; r < 4; r++)
                Cb[(size_t)(rbase + m * 16 + r) * N + cbase + n * 16] =
                    acc[m][n][r] * scale;
}

// ------------------------------------------------- f32 softmax (fallback)
__global__ __launch_bounds__(256)
void softmax_rows(float* __restrict__ P)
{
    const size_t row = blockIdx.x;
    float* p = P + row * 2048;
    const int tid  = threadIdx.x;
    const int lane = tid & 63;
    const int wave = tid >> 6;

    float4 v0 = ((const float4*)p)[tid];
    float4 v1 = ((const float4*)p)[tid + 256];

    float m = fmaxf(fmaxf(fmaxf(v0.x, v0.y), fmaxf(v0.z, v0.w)),
                    fmaxf(fmaxf(v1.x, v1.y), fmaxf(v1.z, v1.w)));
#pragma unroll
    for (int off = 32; off; off >>= 1) m = fmaxf(m, __shfl_xor(m, off));

    __shared__ float sred[4];
    __shared__ float ssum[4];
    if (lane == 0) sred[wave] = m;
    __syncthreads();
    m = fmaxf(fmaxf(sred[0], sred[1]), fmaxf(sred[2], sred[3]));

    v0.x = expf(v0.x - m); v0.y = expf(v0.y - m);
    v0.z = expf(v0.z - m); v0.w = expf(v0.w - m);
    v1.x = expf(v1.x - m); v1.y = expf(v1.y - m);
    v1.z = expf(v1.z - m); v1.w = expf(v1.w - m);

    float s = (v0.x + v0.y + v0.z + v0.w) + (v1.x + v1.y + v1.z + v1.w);
#pragma unroll
    for (int off = 32; off; off >>= 1) s += __shfl_xor(s, off);
    if (lane == 0) ssum[wave] = s;
    __syncthreads();
    s = ssum[0] + ssum[1] + ssum[2] + ssum[3];

    const float r = 1.0f / s;
    v0.x *= r; v0.y *= r; v0.z *= r; v0.w *= r;
    v1.x *= r; v1.y *= r; v1.z *= r; v1.w *= r;

    ((float4*)p)[tid]       = v0;
    ((float4*)p)[tid + 256] = v1;
}

// ---------------------------------------------------------------- launch
extern "C" void kernel_launch(void* const* d_in, const int* in_sizes, int n_in,
                              void* d_out, int out_size, void* d_ws, size_t ws_size,
                              hipStream_t stream)
{
    const float* Q  = (const float*)d_in[0];   // [16, 2048, 256]
    const float* Kk = (const float*)d_in[1];   // [16, 2048, 256]
    const float* V  = (const float*)d_in[2];   // [16, 256, 2048]

    float* outT = (float*)d_out;                        // [16, 256, 2048]
    float* P    = outT + (size_t)16 * 256 * 2048;       // [16, 2048, 2048]

    const size_t nQ = (size_t)16 * 2048 * 256;          // = nK = nV
    const long sQK = (long)2048 * 256;
    const long sP  = (long)2048 * 2048;
    const long sO  = (long)256 * 2048;

    const size_t needKV = 2 * nQ * sizeof(short);       // 33.6 MB

    if (ws_size >= needKV) {
        short* Kb = (short*)d_ws;
        short* Vb = Kb + nQ;

        convert_kv<<<dim3((unsigned)(2 * nQ / 8 / 256)), 256, 0, stream>>>(
            Kk, V, Kb, Vb, nQ / 8);

        fused_attn<<<dim3(256), 512, 0, stream>>>(Q, Kb, Vb, P, outT);
    } else {
        gemm_abt<128, 128, 64><<<dim3(16, 16, 16), 256, 0, stream>>>(
            Q, Kk, P, 2048, 2048, 256, sQK, sQK, sP, 0.0625f);
        softmax_rows<<<dim3(16 * 2048), 256, 0, stream>>>(P);
        gemm_abt<128, 128, 64><<<dim3(16, 2, 16), 256, 0, stream>>>(
            V, P, outT, 256, 2048, 2048, sO, sP, sO, 1.0f);
    }
}

// Round 20
// 157.229 us; speedup vs baseline: 1.0493x; 1.0493x over previous
//
#include <hip/hip_runtime.h>
#include <hip/hip_bf16.h>

// Fused attention: out_t[b,d,n] = sum_m softmax_m(Q[b,n,:]·K[b,m,:]/16)[n,m] * V[b,d,m]
// d_out = out_t (16*256*2048 f32) ++ p_attn (16*2048*2048 f32)
//
// FINAL (R18-verified, 160.5us): fused kernel, 256 blocks x 128 q-rows,
// 8 waves, 144KB LDS. Q converted inline at hoist; K/V pre-converted bf16.
// Pre-loop: l[n] via 16 x 128-row K tiles. Main loop: T4 counted-vmcnt
// barriers, setprio on MFMA clusters, dbuf K/V, swizzled LDS, swapped QK^T,
// NT p_attn stores never drained mid-loop.
// Excluded by measurement: occupancy-2x (R9), producer/consumer (R10),
// two-kernel split (R11), deeper preloop prefetch (R15), asymmetric QK (R16),
// lagged-PV pipeline (R19).

using bf16x8 = __attribute__((ext_vector_type(8))) short;  // 8 bf16 in 4 VGPRs
using f32x4  = __attribute__((ext_vector_type(4))) float;

__device__ __forceinline__ short f2bf(float f) {
    unsigned u = __float_as_uint(f);
    u += 0x7fffu + ((u >> 16) & 1u);   // round-to-nearest-even
    return (short)(u >> 16);
}
__device__ __forceinline__ f32x4 mfma16(bf16x8 a, bf16x8 b, f32x4 c) {
    return __builtin_amdgcn_mfma_f32_16x16x32_bf16(a, b, c, 0, 0, 0);
}

// T4 barriers (m218 pattern): counted waits, never drain NT stores needlessly.
__device__ __forceinline__ void bar_lgkm() {
    asm volatile("s_waitcnt lgkmcnt(0)\n\ts_barrier" ::: "memory");
}
__device__ __forceinline__ void bar_vm4() {
    asm volatile("s_waitcnt vmcnt(4) lgkmcnt(0)\n\ts_barrier" ::: "memory");
}

#define AS1(p) ((const __attribute__((address_space(1))) void*)(p))
#define AS3(p) ((__attribute__((address_space(3))) void*)(p))

constexpr float LOG2E = 1.4426950408889634f;

// ---------------------------------------------------------------- convert K,V
__global__ __launch_bounds__(256)
void convert_kv(const float* __restrict__ K, const float* __restrict__ V,
                short* __restrict__ Kb, short* __restrict__ Vb, size_t n8)
{
    size_t i = (size_t)blockIdx.x * 256 + threadIdx.x;
    const float* src;
    short* dst;
    if (i < n8) { src = K; dst = Kb; }
    else        { i -= n8; src = V; dst = Vb; }
    const f32x4* s4 = (const f32x4*)src;
    f32x4 a = __builtin_nontemporal_load(s4 + i * 2);
    f32x4 b = __builtin_nontemporal_load(s4 + i * 2 + 1);
    bf16x8 v;
    v[0] = f2bf(a[0]); v[1] = f2bf(a[1]); v[2] = f2bf(a[2]); v[3] = f2bf(a[3]);
    v[4] = f2bf(b[0]); v[5] = f2bf(b[1]); v[6] = f2bf(b[2]); v[7] = f2bf(b[3]);
    *(bf16x8*)(dst + i * 8) = v;
}

// ---------------------------------------------------------------- fused
// 256 blocks = (b, nb): 16 x 16 blocks of 128 q-rows. 512 thr, 8 waves.
// LDS: Klds 2x32KB + Vlds 2x32KB + Plds 16KB (lpart aliased) = 144KB.
__global__ __launch_bounds__(512, 2)
void fused_attn(const float* __restrict__ Qf, const short* __restrict__ Kb,
                const short* __restrict__ Vb, float* __restrict__ Pout,
                float* __restrict__ outT)
{
    __shared__ __align__(16) short Klds[2][64 * 256];
    __shared__ __align__(16) short Vlds[2][256 * 64];
    __shared__ __align__(16) short Plds[128 * 64];
    float* lpart = (float*)Plds;                 // [8][32], pre->main only

    const unsigned g  = blockIdx.x;
    const unsigned wg = (g & 7) * 32 + (g >> 3);   // XCD-chunked, bijective
    const int b  = (int)(wg >> 4);
    const int nb = (int)(wg & 15);

    const int tid  = threadIdx.x;
    const int lane = tid & 63;
    const int wave = tid >> 6;
    const int wn  = wave >> 1;
    const int wm  = wave & 1;
    const int l15 = lane & 15;
    const int l4  = lane >> 4;

    const short* Kbase = Kb + (size_t)b * (2048 * 256);
    const short* Vbase = Vb + (size_t)b * (256 * 2048);

    // ---- hoist Q fragments, f32 -> bf16 inline (row=l15, k=l4*8+j).
    const float* Qp = Qf + ((size_t)b * 2048 + (size_t)nb * 128) * 256;
    bf16x8 qf[2][8];
#pragma unroll
    for (int mf = 0; mf < 2; mf++)
#pragma unroll
        for (int ks = 0; ks < 8; ks++) {
            const float* src = Qp + (size_t)(wn * 32 + mf * 16 + l15) * 256
                             + ks * 32 + l4 * 8;
            const f32x4 a = *(const f32x4*)src;
            const f32x4 c = *(const f32x4*)(src + 4);
            bf16x8 v;
            v[0] = f2bf(a[0] * 0.0625f); v[1] = f2bf(a[1] * 0.0625f);
            v[2] = f2bf(a[2] * 0.0625f); v[3] = f2bf(a[3] * 0.0625f);
            v[4] = f2bf(c[0] * 0.0625f); v[5] = f2bf(c[1] * 0.0625f);
            v[6] = f2bf(c[2] * 0.0625f); v[7] = f2bf(c[3] * 0.0625f);
            qf[mf][ks] = v;
        }

    // ---- staging (R8-verified formulas)
    auto stage_k = [&](int t, int buf) {       // 64-row K tile -> Klds[buf]
#pragma unroll
        for (int i = 0; i < 4; i++) {
            int ml = i * 16 + wave * 2 + (lane >> 5);
            int c  = lane & 31;
            int cs = (c & 24) | ((c ^ ml) & 7);
            __builtin_amdgcn_global_load_lds(
                AS1(Kbase + (size_t)(t * 64 + ml) * 256 + cs * 8),
                AS3(&Klds[buf][i * 4096 + wave * 512]), 16, 0, 0);
        }
    };
    auto stage_v = [&](int t, int buf) {       // 256x64 V tile -> Vlds[buf]
#pragma unroll
        for (int i = 0; i < 4; i++) {
            int d  = i * 64 + wave * 8 + (lane >> 3);
            int c  = lane & 7;
            int cs = c ^ (d & 7);
            __builtin_amdgcn_global_load_lds(
                AS1(Vbase + (size_t)d * 2048 + t * 64 + cs * 8),
                AS3(&Vlds[buf][i * 4096 + wave * 512]), 16, 0, 0);
        }
    };
    auto stage_k128 = [&](int t, int which) {  // 128-row K tile (pre-loop)
#pragma unroll
        for (int i = 0; i < 8; i++) {
            int ml = i * 16 + wave * 2 + (lane >> 5);
            int c  = lane & 31;
            int cs = (c & 24) | ((c ^ ml) & 7);
            short* dst = which ? &Vlds[0][0] : &Klds[0][0];
            __builtin_amdgcn_global_load_lds(
                AS1(Kbase + (size_t)(t * 128 + ml) * 256 + cs * 8),
                AS3(dst + i * 4096 + wave * 512), 16, 0, 0);
        }
    };

    // ---- main-loop QK (swapped operands, + setprio)
    auto qkt = [&](int buf, f32x4 sacT[2][2]) {
        __builtin_amdgcn_s_setprio(1);
#pragma unroll
        for (int ks = 0; ks < 8; ks++) {
            bf16x8 kf[2];
#pragma unroll
            for (int nf = 0; nf < 2; nf++) {
                int m  = wm * 32 + nf * 16 + l15;
                int ch = (ks * 4 + l4) ^ (m & 7);
                kf[nf] = *(const bf16x8*)((const char*)&Klds[buf][0] + m * 512 + ch * 16);
            }
#pragma unroll
            for (int mf = 0; mf < 2; mf++)
#pragma unroll
                for (int nf = 0; nf < 2; nf++)
                    sacT[mf][nf] = mfma16(kf[nf], qf[mf][ks], sacT[mf][nf]);
        }
        __builtin_amdgcn_s_setprio(0);
    };
    // ---- pre-loop QK over a 128-row tile
    auto qkt128 = [&](int which, f32x4 sacT[2][4]) {
        const char* kb = which ? (const char*)&Vlds[0][0] : (const char*)&Klds[0][0];
        __builtin_amdgcn_s_setprio(1);
#pragma unroll
        for (int ks = 0; ks < 8; ks++) {
            bf16x8 kf[4];
#pragma unroll
            for (int nf = 0; nf < 4; nf++) {
                int m  = wm * 64 + nf * 16 + l15;
                int ch = (ks * 4 + l4) ^ (m & 7);
                kf[nf] = *(const bf16x8*)(kb + m * 512 + ch * 16);
            }
#pragma unroll
            for (int mf = 0; mf < 2; mf++)
#pragma unroll
                for (int nf = 0; nf < 4; nf++)
                    sacT[mf][nf] = mfma16(kf[nf], qf[mf][ks], sacT[mf][nf]);
        }
        __builtin_amdgcn_s_setprio(0);
    };

    // ================= pre-loop: l[n], 16 x 128-row K tiles =================
    float lacc[2] = {0.f, 0.f};
    stage_k128(0, 0);
    for (int t = 0; t < 16; t++) {
        __syncthreads();                         // tile t staged & drained
        if (t + 1 < 16) stage_k128(t + 1, (t + 1) & 1);
        f32x4 sacT[2][4];
#pragma unroll
        for (int mf = 0; mf < 2; mf++)
#pragma unroll
            for (int nf = 0; nf < 4; nf++)
                sacT[mf][nf] = f32x4{0.f, 0.f, 0.f, 0.f};
        qkt128(t & 1, sacT);
#pragma unroll
        for (int mf = 0; mf < 2; mf++)
#pragma unroll
            for (int nf = 0; nf < 4; nf++)
#pragma unroll
                for (int r = 0; r < 4; r++)
                    lacc[mf] += exp2f(sacT[mf][nf][r] * LOG2E);
    }
    stage_k(0, 0);                               // main K(0); Klds free (t=15 read Vlds)
    // combine 4 l4-groups (same n = l15): butterfly over lane bits 4,5
#pragma unroll
    for (int mf = 0; mf < 2; mf++) {
        lacc[mf] += __shfl_xor(lacc[mf], 16);
        lacc[mf] += __shfl_xor(lacc[mf], 32);
    }
    if (l4 == 0) {
        lpart[wave * 32 + 0 * 16 + l15] = lacc[0];
        lpart[wave * 32 + 1 * 16 + l15] = lacc[1];
    }
    __syncthreads();                             // lpart published; stage_k(0) drained
    stage_v(0, 0);                               // Vlds now safe to overwrite
    float rl[2];
#pragma unroll
    for (int mf = 0; mf < 2; mf++)
        rl[mf] = 1.0f / (lpart[(wn * 2 + 0) * 32 + mf * 16 + l15] +
                         lpart[(wn * 2 + 1) * 32 + mf * 16 + l15]);

    // ================= main loop (T4 counted-vmcnt barriers) ================
    f32x4 oac[4][4];
#pragma unroll
    for (int i = 0; i < 4; i++)
#pragma unroll
        for (int j = 0; j < 4; j++)
            oac[i][j] = f32x4{0.f, 0.f, 0.f, 0.f};

    float* prow = Pout + ((size_t)b * 2048 + (size_t)nb * 128) * 2048;

    __syncthreads();                             // full drain: K(0)+V(0) staged

    for (int t = 0; t < 32; t++) {
        f32x4 sacT[2][2];
#pragma unroll
        for (int mf = 0; mf < 2; mf++)
#pragma unroll
            for (int nf = 0; nf < 2; nf++)
                sacT[mf][nf] = f32x4{0.f, 0.f, 0.f, 0.f};
        qkt(t & 1, sacT);

        // prefetch t+1 immediately: softmax phase + PV cover its latency;
        // retired by the end-of-iter vmcnt(4).
        if (t + 1 < 32) {
            stage_k(t + 1, (t + 1) & 1);
            stage_v(t + 1, (t + 1) & 1);
        }

        f32x4 pv4[2][2];
#pragma unroll
        for (int mf = 0; mf < 2; mf++)
#pragma unroll
            for (int nf = 0; nf < 2; nf++) {
#pragma unroll
                for (int r = 0; r < 4; r++)
                    pv4[mf][nf][r] = exp2f(sacT[mf][nf][r] * LOG2E) * rl[mf];
                short4 ps;
                ps.x = f2bf(pv4[mf][nf][0]); ps.y = f2bf(pv4[mf][nf][1]);
                ps.z = f2bf(pv4[mf][nf][2]); ps.w = f2bf(pv4[mf][nf][3]);
                const int n  = wn * 32 + mf * 16 + l15;
                const int mb = wm * 32 + nf * 16 + l4 * 4;
                const int ch = (mb >> 3) ^ (n & 7);
                *(short4*)((char*)Plds + n * 128 + ch * 16 + (mb & 7) * 2) = ps;
            }
        bar_lgkm();                              // barB: Plds ready; NT/stage in flight

        // p_attn float4 NT stores (newest 4 vmem ops; never waited mid-loop)
#pragma unroll
        for (int mf = 0; mf < 2; mf++)
#pragma unroll
            for (int nf = 0; nf < 2; nf++) {
                const int n  = wn * 32 + mf * 16 + l15;
                const int m  = t * 64 + wm * 32 + nf * 16 + l4 * 4;
                __builtin_nontemporal_store(pv4[mf][nf],
                    (f32x4*)(prow + (size_t)n * 2048 + m));
            }

        // PV: out[d][n] += V[d][m] * P[n][m]
        const char* vb_ = (const char*)&Vlds[t & 1][0];
        __builtin_amdgcn_s_setprio(1);
#pragma unroll
        for (int ksl = 0; ksl < 2; ksl++) {
            bf16x8 vf[4], pf[4];
#pragma unroll
            for (int mf4 = 0; mf4 < 4; mf4++) {
                const int d  = wn * 64 + mf4 * 16 + l15;
                const int ch = (ksl * 4 + l4) ^ (d & 7);
                vf[mf4] = *(const bf16x8*)(vb_ + d * 128 + ch * 16);
            }
#pragma unroll
            for (int nf4 = 0; nf4 < 4; nf4++) {
                const int n  = wm * 64 + nf4 * 16 + l15;
                const int ch = (ksl * 4 + l4) ^ (n & 7);
                pf[nf4] = *(const bf16x8*)((const char*)Plds + n * 128 + ch * 16);
            }
#pragma unroll
            for (int mf4 = 0; mf4 < 4; mf4++)
#pragma unroll
                for (int nf4 = 0; nf4 < 4; nf4++)
                    oac[mf4][nf4] = mfma16(vf[mf4], pf[nf4], oac[mf4][nf4]);
        }
        __builtin_amdgcn_s_setprio(0);

        // end-of-iter: stage(t+1) retired (8 oldest of 12); 4 NT stores remain
        bar_vm4();
    }

    // ---- epilogue: out_t[b][d][nb*128 + n]
    float* op = outT + (size_t)b * (256 * 2048) + (size_t)nb * 128;
#pragma unroll
    for (int mf4 = 0; mf4 < 4; mf4++)
#pragma unroll
        for (int nf4 = 0; nf4 < 4; nf4++)
#pragma unroll
            for (int r = 0; r < 4; r++) {
                int d = wn * 64 + mf4 * 16 + l4 * 4 + r;
                int n = wm * 64 + nf4 * 16 + l15;
                op[(size_t)d * 2048 + n] = oac[mf4][nf4][r];
            }
}

// ------------------------------------------- legacy f32 GEMM (fallback only)
template<int BM, int BN, int BK>
__global__ __launch_bounds__(256)
void gemm_abt(const float* __restrict__ A, const float* __restrict__ B,
              float* __restrict__ C, int M, int N, int K,
              long strideA, long strideB, long strideC, float scale)
{
    const int b  = blockIdx.z;
    const int bm = blockIdx.y;
    const int bn = blockIdx.x;
    A += (size_t)b * strideA;
    B += (size_t)b * strideB;
    C += (size_t)b * strideC;

    constexpr int LDT = BK + 8;
    __shared__ __align__(16) short Alds[BM][LDT];
    __shared__ __align__(16) short Blds[BN][LDT];

    const int tid  = threadIdx.x;
    const int lane = tid & 63;
    const int wave = tid >> 6;
    const int wr   = wave >> 1;
    const int wc   = wave & 1;

    f32x4 acc[4][4];
#pragma unroll
    for (int m = 0; m < 4; m++)
#pragma unroll
        for (int n = 0; n < 4; n++)
            acc[m][n] = f32x4{0.f, 0.f, 0.f, 0.f};

    const float* Ab = A + (size_t)(bm * BM) * K;
    const float* Bb = B + (size_t)(bn * BN) * K;

    const int tr  = tid >> 4;
    const int tc4 = (tid & 15) << 2;

    for (int k0 = 0; k0 < K; k0 += BK) {
        __syncthreads();
#pragma unroll
        for (int r = tr; r < BM; r += 16) {
            const float4 v = *(const float4*)(Ab + (size_t)r * K + k0 + tc4);
            short4 s;
            s.x = f2bf(v.x); s.y = f2bf(v.y); s.z = f2bf(v.z); s.w = f2bf(v.w);
            *(short4*)&Alds[r][tc4] = s;
        }
#pragma unroll
        for (int r = tr; r < BN; r += 16) {
            const float4 v = *(const float4*)(Bb + (size_t)r * K + k0 + tc4);
            short4 s;
            s.x = f2bf(v.x); s.y = f2bf(v.y); s.z = f2bf(v.z); s.w = f2bf(v.w);
            *(short4*)&Blds[r][tc4] = s;
        }
        __syncthreads();

#pragma unroll
        for (int kk = 0; kk < BK; kk += 32) {
            const int ko = kk + ((lane >> 4) << 3);
            bf16x8 af[4], bfr[4];
#pragma unroll
            for (int m = 0; m < 4; m++)
                af[m] = *(const bf16x8*)&Alds[wr * 64 + m * 16 + (lane & 15)][ko];
#pragma unroll
            for (int n = 0; n < 4; n++)
                bfr[n] = *(const bf16x8*)&Blds[wc * 64 + n * 16 + (lane & 15)][ko];
#pragma unroll
            for (int m = 0; m < 4; m++)
#pragma unroll
                for (int n = 0; n < 4; n++)
                    acc[m][n] = __builtin_amdgcn_mfma_f32_16x16x32_bf16(
                        af[m], bfr[n], acc[m][n], 0, 0, 0);
        }
    }

    float* Cb = C + (size_t)(bm * BM) * N + (size_t)bn * BN;
    const int rbase = wr * 64 + ((lane >> 4) << 2);
    const int cbase = wc * 64 + (lane & 15);
#pragma unroll
    for (int m = 0; m < 4; m++)
#pragma unroll
        for (int n = 0; n < 4; n++)
#pragma unroll
            for (int r = 0; r < 4; r++)
                Cb[(size_t)(rbase + m * 16 + r) * N + cbase + n * 16] =
                    acc[m][n][r] * scale;
}

// ------------------------------------------------- f32 softmax (fallback)
__global__ __launch_bounds__(256)
void softmax_rows(float* __restrict__ P)
{
    const size_t row = blockIdx.x;
    float* p = P + row * 2048;
    const int tid  = threadIdx.x;
    const int lane = tid & 63;
    const int wave = tid >> 6;

    float4 v0 = ((const float4*)p)[tid];
    float4 v1 = ((const float4*)p)[tid + 256];

    float m = fmaxf(fmaxf(fmaxf(v0.x, v0.y), fmaxf(v0.z, v0.w)),
                    fmaxf(fmaxf(v1.x, v1.y), fmaxf(v1.z, v1.w)));
#pragma unroll
    for (int off = 32; off; off >>= 1) m = fmaxf(m, __shfl_xor(m, off));

    __shared__ float sred[4];
    __shared__ float ssum[4];
    if (lane == 0) sred[wave] = m;
    __syncthreads();
    m = fmaxf(fmaxf(sred[0], sred[1]), fmaxf(sred[2], sred[3]));

    v0.x = expf(v0.x - m); v0.y = expf(v0.y - m);
    v0.z = expf(v0.z - m); v0.w = expf(v0.w - m);
    v1.x = expf(v1.x - m); v1.y = expf(v1.y - m);
    v1.z = expf(v1.z - m); v1.w = expf(v1.w - m);

    float s = (v0.x + v0.y + v0.z + v0.w) + (v1.x + v1.y + v1.z + v1.w);
#pragma unroll
    for (int off = 32; off; off >>= 1) s += __shfl_xor(s, off);
    if (lane == 0) ssum[wave] = s;
    __syncthreads();
    s = ssum[0] + ssum[1] + ssum[2] + ssum[3];

    const float r = 1.0f / s;
    v0.x *= r; v0.y *= r; v0.z *= r; v0.w *= r;
    v1.x *= r; v1.y *= r; v1.z *= r; v1.w *= r;

    ((float4*)p)[tid]       = v0;
    ((float4*)p)[tid + 256] = v1;
}

// ---------------------------------------------------------------- launch
extern "C" void kernel_launch(void* const* d_in, const int* in_sizes, int n_in,
                              void* d_out, int out_size, void* d_ws, size_t ws_size,
                              hipStream_t stream)
{
    const float* Q  = (const float*)d_in[0];   // [16, 2048, 256]
    const float* Kk = (const float*)d_in[1];   // [16, 2048, 256]
    const float* V  = (const float*)d_in[2];   // [16, 256, 2048]

    float* outT = (float*)d_out;                        // [16, 256, 2048]
    float* P    = outT + (size_t)16 * 256 * 2048;       // [16, 2048, 2048]

    const size_t nQ = (size_t)16 * 2048 * 256;          // = nK = nV
    const long sQK = (long)2048 * 256;
    const long sP  = (long)2048 * 2048;
    const long sO  = (long)256 * 2048;

    const size_t needKV = 2 * nQ * sizeof(short);       // 33.6 MB

    if (ws_size >= needKV) {
        short* Kb = (short*)d_ws;
        short* Vb = Kb + nQ;

        convert_kv<<<dim3((unsigned)(2 * nQ / 8 / 256)), 256, 0, stream>>>(
            Kk, V, Kb, Vb, nQ / 8);

        fused_attn<<<dim3(256), 512, 0, stream>>>(Q, Kb, Vb, P, outT);
    } else {
        gemm_abt<128, 128, 64><<<dim3(16, 16, 16), 256, 0, stream>>>(
            Q, Kk, P, 2048, 2048, 256, sQK, sQK, sP, 0.0625f);
        softmax_rows<<<dim3(16 * 2048), 256, 0, stream>>>(P);
        gemm_abt<128, 128, 64><<<dim3(16, 2, 16), 256, 0, stream>>>(
            V, P, outT, 256, 2048, 2048, sO, sP, sO, 1.0f);
    }
}